// Round 17
// baseline (248.077 us; speedup 1.0000x reference)
//
#include <hip/hip_runtime.h>
#include <hip/hip_bf16.h>

typedef __bf16 bf16_t;
typedef bf16_t bf16x8 __attribute__((ext_vector_type(8)));
typedef float f32x4 __attribute__((ext_vector_type(4)));
typedef float f32x16 __attribute__((ext_vector_type(16)));
typedef unsigned short u16;
typedef unsigned int u32;

#define B_    2
#define S_    2048
#define HID   2048
#define NQKV  3072          // (16 + 2*4) * 128
#define HQ_   16
#define HKV_  4
#define D_    128
// D^-0.5 * log2(e): folded into Q so softmax runs in exp2 domain
#define QSCALE_ 0.12751879526600565f

__device__ __forceinline__ u16 f2b(float f) {
    __hip_bfloat16 h = __float2bfloat16(f);
    return *reinterpret_cast<u16*>(&h);
}
__device__ __forceinline__ float b2f(u32 u) {
    u32 v = u << 16;
    float f;
    __builtin_memcpy(&f, &v, 4);
    return f;
}
__device__ __forceinline__ float max3f(float a, float b, float c) {
    return fmaxf(fmaxf(a, b), c);    // clang fuses to v_max3_f32
}

// ---------------------------------------------------------------- fused f32 -> bf16 (3 buffers, 1 launch)
__global__ __launch_bounds__(256) void cvt3_f32_bf16(const float* __restrict__ i0, u16* __restrict__ o0, int n0,
                                                     const float* __restrict__ i1, u16* __restrict__ o1, int n1,
                                                     const float* __restrict__ i2, u16* __restrict__ o2, int n2) {
    int i = blockIdx.x * 256 + threadIdx.x;
    const float* src; u16* dst; int idx;
    if (i < n0)           { src = i0; dst = o0; idx = i; }
    else if (i < n0 + n1) { src = i1; dst = o1; idx = i - n0; }
    else if (i < n0 + n1 + n2) { src = i2; dst = o2; idx = i - n0 - n1; }
    else return;
    float4 v = reinterpret_cast<const float4*>(src)[idx];
    ushort4 o;
    o.x = f2b(v.x); o.y = f2b(v.y); o.z = f2b(v.z); o.w = f2b(v.w);
    reinterpret_cast<ushort4*>(dst)[idx] = o;
}

// ---------------------------------------------------------------- GEMM 128x128, BK=64, 4 waves (2Mx2N, wave 64x64)
// Paired-row LDS layout (R16-verified: conflicts ~0, ~85% of b128 LDS-pipe
// ceiling). A: MxK row-major, B: NxK row-major (B^T). C: f32 or bf16.
template<bool BF16OUT>
__global__ __launch_bounds__(256, 2) void gemm128sq(const u16* __restrict__ A,
                                                    const u16* __restrict__ Bm,
                                                    void* __restrict__ Cv,
                                                    int M, int N, int K) {
    __shared__ __align__(16) char smem[2][32768];   // [buf][A 16KB | B 16KB]

    const int tid  = threadIdx.x;
    const int lane = tid & 63;
    const int wid  = tid >> 6;                      // 0..3
    const int wr = wid >> 1, wc = wid & 1;          // wave tile 64M x 64N
    const int l31 = lane & 31, hi = lane >> 5;

    const int m0 = blockIdx.x * 128, n0 = blockIdx.y * 128;

    int stOff[4];
    #pragma unroll
    for (int p = 0; p < 4; ++p) {
        int c = tid + p * 256;
        int prow = c >> 4;
        int raw = (c & 15) ^ (prow & 15);
        stOff[p] = (2 * prow + (raw >> 3)) * K + (raw & 7) * 8;
    }
    const u16* aB2 = A  + (size_t)m0 * K;
    const u16* bB2 = Bm + (size_t)n0 * K;

    auto glds = [&](const u16* g, u16* l) {
        __builtin_amdgcn_global_load_lds(
            (const __attribute__((address_space(1))) void*)g,
            (__attribute__((address_space(3))) void*)l, 16, 0, 0);
    };
    auto stage = [&](int buf, int k0) {
        u16* ad = (u16*)smem[buf] + tid * 8;
        u16* bd = ad + 8192;                        // B at +16KB
        #pragma unroll
        for (int p = 0; p < 4; ++p) glds(aB2 + k0 + stOff[p], ad + p * 2048);
        #pragma unroll
        for (int p = 0; p < 4; ++p) glds(bB2 + k0 + stOff[p], bd + p * 2048);
    };

    f32x16 acc[2][2] = {};                          // 64 VGPR
    const int KT = K >> 6;

    stage(0, 0);                                    // tile 0 in flight

    const int prw   = l31 >> 1;                     // prow&15 at read
    const int phalf = (l31 & 1) << 7;               // which 128B half

    for (int t = 0; t < KT; ++t) {
        const int cur = t & 1;
        if (t + 1 < KT) {
            stage(cur ^ 1, (t + 1) << 6);           // full-iter flight for t+1
            asm volatile("s_waitcnt vmcnt(8)" ::: "memory");   // tile t landed
        } else {
            asm volatile("s_waitcnt vmcnt(0)" ::: "memory");
        }
        __builtin_amdgcn_s_barrier();

        const char* aT = smem[cur];
        const char* bT = aT + 16384;

        #pragma unroll
        for (int ks = 0; ks < 4; ++ks) {
            const int kb = (phalf | (ks * 32 + hi * 16)) ^ (prw << 4);
            bf16x8 af0 = *(const bf16x8*)(aT + (wr * 32 +      prw) * 256 + kb);
            bf16x8 af1 = *(const bf16x8*)(aT + (wr * 32 + 16 + prw) * 256 + kb);
            bf16x8 bf0 = *(const bf16x8*)(bT + (wc * 32 +      prw) * 256 + kb);
            bf16x8 bf1 = *(const bf16x8*)(bT + (wc * 32 + 16 + prw) * 256 + kb);
            __builtin_amdgcn_s_setprio(1);
            acc[0][0] = __builtin_amdgcn_mfma_f32_32x32x16_bf16(af0, bf0, acc[0][0], 0, 0, 0);
            acc[0][1] = __builtin_amdgcn_mfma_f32_32x32x16_bf16(af0, bf1, acc[0][1], 0, 0, 0);
            acc[1][0] = __builtin_amdgcn_mfma_f32_32x32x16_bf16(af1, bf0, acc[1][0], 0, 0, 0);
            acc[1][1] = __builtin_amdgcn_mfma_f32_32x32x16_bf16(af1, bf1, acc[1][1], 0, 0, 0);
            __builtin_amdgcn_s_setprio(0);
        }
        __builtin_amdgcn_s_barrier();
    }

    // ---- epilogue: 32x32 C/D layout: row=(r&3)+8*(r>>2)+4*hi, col=l31
    #pragma unroll
    for (int mb = 0; mb < 2; ++mb)
        #pragma unroll
        for (int nb = 0; nb < 2; ++nb) {
            const int n = n0 + wc * 64 + nb * 32 + l31;
            #pragma unroll
            for (int r = 0; r < 16; ++r) {
                int m = m0 + wr * 64 + mb * 32 + (r & 3) + 8 * (r >> 2) + 4 * hi;
                if (BF16OUT)
                    ((u16*)Cv)[(size_t)m * N + n] = f2b(acc[mb][nb][r]);
                else
                    ((float*)Cv)[(size_t)m * N + n] = acc[mb][nb][r];
            }
        }
}

// ---------------------------------------------------------------- RoPE (interleaved) + RMSNorm + split/relayout (bf16 qkv in)
__global__ __launch_bounds__(256) void rope_norm_split(const u16* __restrict__ qkvb,
                                                       const float* __restrict__ cosb,
                                                       const float* __restrict__ sinb,
                                                       const float* __restrict__ nw,
                                                       u16* __restrict__ qb,
                                                       u16* __restrict__ kb,
                                                       u16* __restrict__ vb) {
    const int row  = blockIdx.x;          // b*S + s
    const int b    = row >> 11;
    const int s    = row & 2047;
    const int wave = threadIdx.x >> 6;
    const int lane = threadIdx.x & 63;
    const u16* base = qkvb + (size_t)row * NQKV;

    const float c0 = cosb[s * 128 + lane];
    const float c1 = cosb[s * 128 + 64 + lane];
    const float s0 = sinb[s * 128 + lane];
    const float s1 = sinb[s * 128 + 64 + lane];
    const float w0 = nw[2 * lane];
    const float w1 = nw[2 * lane + 1];

    for (int h = wave; h < HQ_ + HKV_; h += 4) {
        u32 xw = *(const u32*)(base + h * 128 + 2 * lane);
        float x0 = b2f(xw & 0xffffu), x1 = b2f(xw >> 16);
        float y0 = x0 * c0 - x1 * s0;
        float y1 = x1 * c1 + x0 * s1;
        float ss = y0 * y0 + y1 * y1;
        #pragma unroll
        for (int off = 32; off; off >>= 1) ss += __shfl_xor(ss, off);
        float r = rsqrtf(ss * (1.0f / 128.0f) + 1e-6f);
        float o0 = y0 * r * w0, o1 = y1 * r * w1;
        if (h < HQ_) {
            u32 pack = (u32)f2b(o0 * QSCALE_) | ((u32)f2b(o1 * QSCALE_) << 16);
            *(u32*)(qb + ((size_t)(b * HQ_ + h) * S_ + s) * D_ + 2 * lane) = pack;
        } else {
            u32 pack = (u32)f2b(o0) | ((u32)f2b(o1) << 16);
            *(u32*)(kb + ((size_t)(b * HKV_ + (h - HQ_)) * S_ + s) * D_ + 2 * lane) = pack;
        }
    }
    {
        int h = wave;
        u32 xw = *(const u32*)(base + (HQ_ + HKV_) * 128 + h * 128 + 2 * lane);
        *(u32*)(vb + ((size_t)(b * HKV_ + h) * S_ + s) * D_ + 2 * lane) = xw;
    }
}

// ---------------------------------------------------------------- V transpose: (B,HKV,S,D) -> (B,HKV,D,S)
__global__ __launch_bounds__(256) void transpose_v(const u16* __restrict__ vb,
                                                   u16* __restrict__ vtb) {
    __shared__ u16 t[64][72];
    const int s0 = blockIdx.x * 64, d0 = blockIdx.y * 64, bh = blockIdx.z;
    const u16* src = vb  + (size_t)bh * S_ * D_;
    u16*       dst = vtb + (size_t)bh * D_ * S_;
    const int tid = threadIdx.x;

    {
        int r = tid >> 3, c8 = (tid & 7) * 8;
        #pragma unroll
        for (int p = 0; p < 2; p++) {
            int rr = r + p * 32;
            *(uint4*)&t[rr][c8] = *(const uint4*)(src + (size_t)(s0 + rr) * D_ + d0 + c8);
        }
    }
    __syncthreads();
    {
        int dd = tid & 63;
        int sb = (tid >> 6) * 8;
        #pragma unroll
        for (int p = 0; p < 2; p++) {
            int ss8 = sb + p * 32;
            union { u16 u[8]; uint4 v; } pk;
            #pragma unroll
            for (int j = 0; j < 8; j++) pk.u[j] = t[ss8 + j][dd];
            *(uint4*)(dst + (size_t)(d0 + dd) * S_ + s0 + ss8) = pk.v;
        }
    }
}

// ---------------------------------------------------------------- causal GQA flash attention v8.1
// R13/R16 structure + critical-path nudges: (1) sc partial-sum adds moved
// after V-prefetch issue (V ds_reads fly earlier); (2) max tree via
// v_max3_f32 nesting (15 serial fmax -> 8 ops).
__global__ __launch_bounds__(256, 2) void attn_fwd3(const u16* __restrict__ qb,
                                                    const u16* __restrict__ kb,
                                                    const u16* __restrict__ vtb,
                                                    u16* __restrict__ attn) {
    __shared__ __align__(16) u16 Ks[2][64 * 128];   // 32KB (reused as O bounce)
    __shared__ __align__(16) u16 Vs[2][64 * 128];   // 32KB, [64 rows][256B]

    const int bh  = blockIdx.y;
    const int qt  = (bh < 16) ? (15 - (int)blockIdx.x) : (int)blockIdx.x;
    const int b   = bh >> 4, hq = bh & 15, hkv = hq >> 2;
    const int tid = threadIdx.x;
    const int wave = tid >> 6, lane = tid & 63;
    const int l31 = lane & 31, hi = lane >> 5;
    const int swzK = (l31 & 15) << 4;               // 4-bit K swizzle
    const int swzO = (l31 & 7) << 4;                // epilogue bounce

    const u16* Q  = qb  + (size_t)(b * HQ_  + hq ) * S_ * D_;
    const u16* Kp = kb  + (size_t)(b * HKV_ + hkv) * S_ * D_;
    const u16* Vt = vtb + (size_t)(b * HKV_ + hkv) * D_ * S_;
    const int q0w = qt * 128 + wave * 32;
    const int qg  = q0w + l31;            // this lane's q row

    int kSrc[4], vSrc[4], cLds[4];
    #pragma unroll
    for (int p = 0; p < 4; p++) {
        int c = tid + p * 256;
        int kr = c >> 4;                                   // K row 0..63
        int kc = ((c & 15) * 16) ^ ((kr & 15) << 4);       // bytes in row
        kSrc[p] = kr * D_ + (kc >> 1);
        int vr = c >> 4;                                   // V LDS row 0..63
        int raw = (c & 15) ^ (vr & 15);                    // 16B slot pre-swizzle
        int vd = 2 * vr + (raw >> 3);                      // d index
        vSrc[p] = vd * S_ + (raw & 7) * 8;                 // elem offset (kv chunk)
        cLds[p] = c * 16;
    }

    auto STAGE = [&](int buf, int kv0s) {
        const u16* kbase = Kp + (size_t)kv0s * D_;
        const u16* vbase = Vt + kv0s;
        #pragma unroll
        for (int p = 0; p < 4; p++)
            __builtin_amdgcn_global_load_lds(
                (const __attribute__((address_space(1))) void*)(kbase + kSrc[p]),
                (__attribute__((address_space(3))) void*)((char*)Ks[buf] + cLds[p]), 16, 0, 0);
        #pragma unroll
        for (int p = 0; p < 4; p++)
            __builtin_amdgcn_global_load_lds(
                (const __attribute__((address_space(1))) void*)(vbase + vSrc[p]),
                (__attribute__((address_space(3))) void*)((char*)Vs[buf] + cLds[p]), 16, 0, 0);
    };

    bf16x8 qf[8];
    #pragma unroll
    for (int ds = 0; ds < 8; ds++)
        qf[ds] = *(const bf16x8*)(Q + (size_t)qg * D_ + ds * 16 + hi * 8);

    float m_run = -1e30f, l_run = 0.f;
    f32x16 oacc[4] = {};

    const int nkt = 2 * qt + 2;
    STAGE(0, 0);

    for (int kt = 0; kt < nkt; kt++) {
        const int cur = kt & 1;
        const int kv0 = kt * 64;
        if (kt + 1 < nkt) {
            STAGE(cur ^ 1, kv0 + 64);
            asm volatile("s_waitcnt vmcnt(8)" ::: "memory");
        } else {
            asm volatile("s_waitcnt vmcnt(0)" ::: "memory");
        }
        __builtin_amdgcn_s_barrier();

        // ---- batch K-fragment reads (2-way banked -> conflict-free)
        const char* ksb = (const char*)Ks[cur];
        const char* vsb = (const char*)Vs[cur];
        const char* rb0 = ksb + l31 * 256;
        const char* rb1 = rb0 + 32 * 256;
        bf16x8 kA[8], kB[8];
        #pragma unroll
        for (int ds = 0; ds < 8; ds++) kA[ds] = *(const bf16x8*)(rb0 + ((ds * 32 + hi * 16) ^ swzK));
        #pragma unroll
        for (int ds = 0; ds < 8; ds++) kB[ds] = *(const bf16x8*)(rb1 + ((ds * 32 + hi * 16) ^ swzK));

        f32x16 s0a = {}, s0b = {}, s1a = {}, s1b = {};
        __builtin_amdgcn_s_setprio(1);
        #pragma unroll
        for (int ds = 0; ds < 4; ds++) {
            s0a = __builtin_amdgcn_mfma_f32_32x32x16_bf16(kA[ds],     qf[ds],     s0a, 0, 0, 0);
            s0b = __builtin_amdgcn_mfma_f32_32x32x16_bf16(kA[ds + 4], qf[ds + 4], s0b, 0, 0, 0);
            s1a = __builtin_amdgcn_mfma_f32_32x32x16_bf16(kB[ds],     qf[ds],     s1a, 0, 0, 0);
            s1b = __builtin_amdgcn_mfma_f32_32x32x16_bf16(kB[ds + 4], qf[ds + 4], s1b, 0, 0, 0);
        }
        __builtin_amdgcn_s_setprio(0);

        // ---- V fragments first (ds_reads issue before the sc adds)
        bf16x8 vf[4][4];
        {
            const int vrow = (l31 >> 1);
            const int vswz = vrow << 4;
            const int dlo  = (l31 & 1) << 7;
            #pragma unroll
            for (int ks = 0; ks < 4; ks++)
                #pragma unroll
                for (int d4 = 0; d4 < 4; d4++)
                    vf[ks][d4] = *(const bf16x8*)(vsb + (d4 * 16 + vrow) * 256
                                                      + ((dlo | (ks * 32 + hi * 16)) ^ vswz));
        }

        f32x16 sc[2];
        sc[0] = s0a + s0b;
        sc[1] = s1a + s1b;
        __builtin_amdgcn_s_barrier();

        if (kv0 + 63 > q0w) {
            #pragma unroll
            for (int blk = 0; blk < 2; blk++)
                #pragma unroll
                for (int r = 0; r < 16; r++) {
                    int kvg = kv0 + blk * 32 + (r & 3) + 8 * (r >> 2) + 4 * hi;
                    if (kvg > qg) sc[blk][r] = -1e30f;
                }
        }

        // ---- row max: v_max3 tree (8 ops vs 15)
        float t16[16];
        #pragma unroll
        for (int r = 0; r < 16; r++) t16[r] = fmaxf(sc[0][r], sc[1][r]);
        float v1 = max3f(t16[0],  t16[1],  t16[2]);
        float v2 = max3f(t16[3],  t16[4],  t16[5]);
        float v3 = max3f(t16[6],  t16[7],  t16[8]);
        float v4 = max3f(t16[9],  t16[10], t16[11]);
        float v5 = max3f(t16[12], t16[13], t16[14]);
        float mt = fmaxf(max3f(max3f(v1, v2, v3), v4, v5), t16[15]);
        mt = fmaxf(mt, __shfl_xor(mt, 32));

        bool noDefer = !__all(mt <= m_run + 8.0f);
        float mnew = m_run;
        if (noDefer) {
            mnew = fmaxf(m_run, mt);
            float alpha = __builtin_amdgcn_exp2f(m_run - mnew);
            l_run *= alpha;
            #pragma unroll
            for (int d4 = 0; d4 < 4; d4++)
                #pragma unroll
                for (int r = 0; r < 16; r++) oacc[d4][r] *= alpha;
            m_run = mnew;
        }

        float la = 0.f;
        u32 pk0[8], pk1[8];
        #pragma unroll
        for (int g = 0; g < 4; g++)
            #pragma unroll
            for (int e = 0; e < 2; e++) {
                float a0 = __builtin_amdgcn_exp2f(sc[0][g * 4 + 2 * e]     - mnew);
                float b0 = __builtin_amdgcn_exp2f(sc[0][g * 4 + 2 * e + 1] - mnew);
                float a1 = __builtin_amdgcn_exp2f(sc[1][g * 4 + 2 * e]     - mnew);
                float b1 = __builtin_amdgcn_exp2f(sc[1][g * 4 + 2 * e + 1] - mnew);
                la += (a0 + b0) + (a1 + b1);
                pk0[g * 2 + e] = (u32)f2b(a0) | ((u32)f2b(b0) << 16);
                pk1[g * 2 + e] = (u32)f2b(a1) | ((u32)f2b(b1) << 16);
            }
        la += __shfl_xor(la, 32);
        l_run += la;

        u32 qk0[8], qk1[8];
        #pragma unroll
        for (int i = 0; i < 8; i++) {
            qk0[i] = __shfl_xor(pk0[i], 32);
            qk1[i] = __shfl_xor(pk1[i], 32);
        }

        #pragma unroll
        for (int ks = 0; ks < 4; ks++) {
            const int i0 = (ks & 1) * 4;
            union { u32 w[4]; bf16x8 v; } pfv;
            if (ks & 2) {
                pfv.w[0] = hi ? qk1[i0 + 2] : pk1[i0 + 0];
                pfv.w[1] = hi ? qk1[i0 + 3] : pk1[i0 + 1];
                pfv.w[2] = hi ? pk1[i0 + 2] : qk1[i0 + 0];
                pfv.w[3] = hi ? pk1[i0 + 3] : qk1[i0 + 1];
            } else {
                pfv.w[0] = hi ? qk0[i0 + 2] : pk0[i0 + 0];
                pfv.w[1] = hi ? qk0[i0 + 3] : pk0[i0 + 1];
                pfv.w[2] = hi ? pk0[i0 + 2] : qk0[i0 + 0];
                pfv.w[3] = hi ? pk0[i0 + 3] : qk0[i0 + 1];
            }
            __builtin_amdgcn_s_setprio(1);
            #pragma unroll
            for (int d4 = 0; d4 < 4; d4++)
                oacc[d4] = __builtin_amdgcn_mfma_f32_32x32x16_bf16(vf[ks][d4], pfv.v, oacc[d4], 0, 0, 0);
            __builtin_amdgcn_s_setprio(0);
        }
    }

    const float inv = 1.0f / l_run;
    u16* sl = (u16*)Ks + wave * (32 * 128);
    #pragma unroll
    for (int d4 = 0; d4 < 4; d4++)
        #pragma unroll
        for (int rp = 0; rp < 8; rp++) {
            int dbyte = d4 * 64 + 16 * (rp >> 1) + 8 * hi + 4 * (rp & 1);
            u32 w = (u32)f2b(oacc[d4][rp * 2] * inv)
                  | ((u32)f2b(oacc[d4][rp * 2 + 1] * inv) << 16);
            *(u32*)((char*)sl + l31 * 256 + (dbyte ^ swzO)) = w;
        }
    #pragma unroll
    for (int j = 0; j < 8; j++) {
        int c = lane + j * 64;
        int qL = c >> 4, dc = c & 15;
        uint4 v = *(uint4*)((char*)sl + qL * 256 + ((dc * 16) ^ ((qL & 7) << 4)));
        int qrow = qt * 128 + wave * 32 + qL;
        *(uint4*)(attn + (size_t)(b * S_ + qrow) * (HQ_ * D_) + hq * D_ + dc * 8) = v;
    }
}

// ---------------------------------------------------------------- launcher
extern "C" void kernel_launch(void* const* d_in, const int* in_sizes, int n_in,
                              void* d_out, int out_size, void* d_ws, size_t ws_size,
                              hipStream_t stream) {
    const float* hidden = (const float*)d_in[0];
    const float* cosb   = (const float*)d_in[1];
    const float* sinb   = (const float*)d_in[2];
    const float* qkvw   = (const float*)d_in[3];
    const float* nw     = (const float*)d_in[4];
    const float* ow     = (const float*)d_in[5];
    float* out = (float*)d_out;

    const size_t M  = (size_t)B_ * S_;             // 4096
    char* ws = (char*)d_ws;
    size_t off = 0;
    u16*   hb    = (u16*)(ws + off); off += M * HID * 2;                     // 16 MB (reused as attn)
    u16*   wqkvb = (u16*)(ws + off); off += (size_t)NQKV * HID * 2;          // 12 MB
    u16*   wob   = (u16*)(ws + off); off += (size_t)HID * (HQ_ * D_) * 2;    // 8 MB
    u16*   qkvb  = (u16*)(ws + off); off += M * NQKV * 2;                    // 24 MB (bf16)
    u16*   qb2   = (u16*)(ws + off); off += (size_t)B_ * HQ_  * S_ * D_ * 2; // 16 MB
    u16*   kb2   = (u16*)(ws + off); off += (size_t)B_ * HKV_ * S_ * D_ * 2; // 4 MB
    u16*   vb2   = (u16*)(ws + off); off += (size_t)B_ * HKV_ * S_ * D_ * 2; // 4 MB
    u16*   vtb   = (u16*)(ws + off); off += (size_t)B_ * HKV_ * S_ * D_ * 2; // 4 MB
    u16*   attn  = hb;

    // fused conversions (1 launch)
    {
        int n0 = (int)(M * HID / 4);
        int n1 = NQKV * HID / 4;
        int n2 = HID * (HQ_ * D_) / 4;
        int nt = n0 + n1 + n2;
        cvt3_f32_bf16<<<(nt + 255) / 256, 256, 0, stream>>>(hidden, hb, n0,
                                                            qkvw, wqkvb, n1,
                                                            ow, wob, n2);
    }

    // QKV projection -> bf16 qkv (grid 32x24 = 768 blocks)
    gemm128sq<true><<<dim3(M / 128, NQKV / 128), 256, 0, stream>>>(
        hb, wqkvb, qkvb, (int)M, NQKV, HID);

    rope_norm_split<<<(int)M, 256, 0, stream>>>(qkvb, cosb, sinb, nw, qb2, kb2, vb2);

    transpose_v<<<dim3(S_ / 64, D_ / 64, B_ * HKV_), 256, 0, stream>>>(vb2, vtb);

    attn_fwd3<<<dim3(16, B_ * HQ_), 256, 0, stream>>>(qb2, kb2, vtb, attn);

    // output projection -> f32 d_out (grid 32x16 = 512 blocks)
    gemm128sq<false><<<dim3(M / 128, HID / 128), 256, 0, stream>>>(
        attn, wob, out, (int)M, HID, HQ_ * D_);
}

// Round 18
// 214.433 us; speedup vs baseline: 1.1569x; 1.1569x over previous
//
#include <hip/hip_runtime.h>
#include <hip/hip_bf16.h>

typedef __bf16 bf16_t;
typedef bf16_t bf16x8 __attribute__((ext_vector_type(8)));
typedef float f32x4 __attribute__((ext_vector_type(4)));
typedef float f32x16 __attribute__((ext_vector_type(16)));
typedef unsigned short u16;
typedef unsigned int u32;

#define B_    2
#define S_    2048
#define HID   2048
#define NQKV  3072          // (16 + 2*4) * 128
#define HQ_   16
#define HKV_  4
#define D_    128
// D^-0.5 * log2(e): folded into Q so softmax runs in exp2 domain
#define QSCALE_ 0.12751879526600565f

__device__ __forceinline__ u16 f2b(float f) {
    __hip_bfloat16 h = __float2bfloat16(f);
    return *reinterpret_cast<u16*>(&h);
}
__device__ __forceinline__ float b2f(u32 u) {
    u32 v = u << 16;
    float f;
    __builtin_memcpy(&f, &v, 4);
    return f;
}

// ---------------------------------------------------------------- fused f32 -> bf16 (3 buffers, 1 launch)
__global__ __launch_bounds__(256) void cvt3_f32_bf16(const float* __restrict__ i0, u16* __restrict__ o0, int n0,
                                                     const float* __restrict__ i1, u16* __restrict__ o1, int n1,
                                                     const float* __restrict__ i2, u16* __restrict__ o2, int n2) {
    int i = blockIdx.x * 256 + threadIdx.x;
    const float* src; u16* dst; int idx;
    if (i < n0)           { src = i0; dst = o0; idx = i; }
    else if (i < n0 + n1) { src = i1; dst = o1; idx = i - n0; }
    else if (i < n0 + n1 + n2) { src = i2; dst = o2; idx = i - n0 - n1; }
    else return;
    float4 v = reinterpret_cast<const float4*>(src)[idx];
    ushort4 o;
    o.x = f2b(v.x); o.y = f2b(v.y); o.z = f2b(v.z); o.w = f2b(v.w);
    reinterpret_cast<ushort4*>(dst)[idx] = o;
}

// ---------------------------------------------------------------- GEMM 128x128, BK=64, 4 waves (2Mx2N, wave 64x64)
// Paired-row LDS layout (R16-verified: conflicts ~0, ~85% of b128 LDS-pipe
// ceiling). A: MxK row-major, B: NxK row-major (B^T). C: f32 or bf16.
template<bool BF16OUT>
__global__ __launch_bounds__(256, 2) void gemm128sq(const u16* __restrict__ A,
                                                    const u16* __restrict__ Bm,
                                                    void* __restrict__ Cv,
                                                    int M, int N, int K) {
    __shared__ __align__(16) char smem[2][32768];   // [buf][A 16KB | B 16KB]

    const int tid  = threadIdx.x;
    const int lane = tid & 63;
    const int wid  = tid >> 6;                      // 0..3
    const int wr = wid >> 1, wc = wid & 1;          // wave tile 64M x 64N
    const int l31 = lane & 31, hi = lane >> 5;

    const int m0 = blockIdx.x * 128, n0 = blockIdx.y * 128;

    int stOff[4];
    #pragma unroll
    for (int p = 0; p < 4; ++p) {
        int c = tid + p * 256;
        int prow = c >> 4;
        int raw = (c & 15) ^ (prow & 15);
        stOff[p] = (2 * prow + (raw >> 3)) * K + (raw & 7) * 8;
    }
    const u16* aB2 = A  + (size_t)m0 * K;
    const u16* bB2 = Bm + (size_t)n0 * K;

    auto glds = [&](const u16* g, u16* l) {
        __builtin_amdgcn_global_load_lds(
            (const __attribute__((address_space(1))) void*)g,
            (__attribute__((address_space(3))) void*)l, 16, 0, 0);
    };
    auto stage = [&](int buf, int k0) {
        u16* ad = (u16*)smem[buf] + tid * 8;
        u16* bd = ad + 8192;                        // B at +16KB
        #pragma unroll
        for (int p = 0; p < 4; ++p) glds(aB2 + k0 + stOff[p], ad + p * 2048);
        #pragma unroll
        for (int p = 0; p < 4; ++p) glds(bB2 + k0 + stOff[p], bd + p * 2048);
    };

    f32x16 acc[2][2] = {};                          // 64 VGPR
    const int KT = K >> 6;

    stage(0, 0);                                    // tile 0 in flight

    const int prw   = l31 >> 1;                     // prow&15 at read
    const int phalf = (l31 & 1) << 7;               // which 128B half

    for (int t = 0; t < KT; ++t) {
        const int cur = t & 1;
        if (t + 1 < KT) {
            stage(cur ^ 1, (t + 1) << 6);           // full-iter flight for t+1
            asm volatile("s_waitcnt vmcnt(8)" ::: "memory");   // tile t landed
        } else {
            asm volatile("s_waitcnt vmcnt(0)" ::: "memory");
        }
        __builtin_amdgcn_s_barrier();

        const char* aT = smem[cur];
        const char* bT = aT + 16384;

        #pragma unroll
        for (int ks = 0; ks < 4; ++ks) {
            const int kb = (phalf | (ks * 32 + hi * 16)) ^ (prw << 4);
            bf16x8 af0 = *(const bf16x8*)(aT + (wr * 32 +      prw) * 256 + kb);
            bf16x8 af1 = *(const bf16x8*)(aT + (wr * 32 + 16 + prw) * 256 + kb);
            bf16x8 bf0 = *(const bf16x8*)(bT + (wc * 32 +      prw) * 256 + kb);
            bf16x8 bf1 = *(const bf16x8*)(bT + (wc * 32 + 16 + prw) * 256 + kb);
            __builtin_amdgcn_s_setprio(1);
            acc[0][0] = __builtin_amdgcn_mfma_f32_32x32x16_bf16(af0, bf0, acc[0][0], 0, 0, 0);
            acc[0][1] = __builtin_amdgcn_mfma_f32_32x32x16_bf16(af0, bf1, acc[0][1], 0, 0, 0);
            acc[1][0] = __builtin_amdgcn_mfma_f32_32x32x16_bf16(af1, bf0, acc[1][0], 0, 0, 0);
            acc[1][1] = __builtin_amdgcn_mfma_f32_32x32x16_bf16(af1, bf1, acc[1][1], 0, 0, 0);
            __builtin_amdgcn_s_setprio(0);
        }
        __builtin_amdgcn_s_barrier();
    }

    // ---- epilogue: 32x32 C/D layout: row=(r&3)+8*(r>>2)+4*hi, col=l31
    #pragma unroll
    for (int mb = 0; mb < 2; ++mb)
        #pragma unroll
        for (int nb = 0; nb < 2; ++nb) {
            const int n = n0 + wc * 64 + nb * 32 + l31;
            #pragma unroll
            for (int r = 0; r < 16; ++r) {
                int m = m0 + wr * 64 + mb * 32 + (r & 3) + 8 * (r >> 2) + 4 * hi;
                if (BF16OUT)
                    ((u16*)Cv)[(size_t)m * N + n] = f2b(acc[mb][nb][r]);
                else
                    ((float*)Cv)[(size_t)m * N + n] = acc[mb][nb][r];
            }
        }
}

// ---------------------------------------------------------------- RoPE (interleaved) + RMSNorm + split/relayout (bf16 qkv in)
__global__ __launch_bounds__(256) void rope_norm_split(const u16* __restrict__ qkvb,
                                                       const float* __restrict__ cosb,
                                                       const float* __restrict__ sinb,
                                                       const float* __restrict__ nw,
                                                       u16* __restrict__ qb,
                                                       u16* __restrict__ kb,
                                                       u16* __restrict__ vb) {
    const int row  = blockIdx.x;          // b*S + s
    const int b    = row >> 11;
    const int s    = row & 2047;
    const int wave = threadIdx.x >> 6;
    const int lane = threadIdx.x & 63;
    const u16* base = qkvb + (size_t)row * NQKV;

    const float c0 = cosb[s * 128 + lane];
    const float c1 = cosb[s * 128 + 64 + lane];
    const float s0 = sinb[s * 128 + lane];
    const float s1 = sinb[s * 128 + 64 + lane];
    const float w0 = nw[2 * lane];
    const float w1 = nw[2 * lane + 1];

    for (int h = wave; h < HQ_ + HKV_; h += 4) {
        u32 xw = *(const u32*)(base + h * 128 + 2 * lane);
        float x0 = b2f(xw & 0xffffu), x1 = b2f(xw >> 16);
        float y0 = x0 * c0 - x1 * s0;
        float y1 = x1 * c1 + x0 * s1;
        float ss = y0 * y0 + y1 * y1;
        #pragma unroll
        for (int off = 32; off; off >>= 1) ss += __shfl_xor(ss, off);
        float r = rsqrtf(ss * (1.0f / 128.0f) + 1e-6f);
        float o0 = y0 * r * w0, o1 = y1 * r * w1;
        if (h < HQ_) {
            u32 pack = (u32)f2b(o0 * QSCALE_) | ((u32)f2b(o1 * QSCALE_) << 16);
            *(u32*)(qb + ((size_t)(b * HQ_ + h) * S_ + s) * D_ + 2 * lane) = pack;
        } else {
            u32 pack = (u32)f2b(o0) | ((u32)f2b(o1) << 16);
            *(u32*)(kb + ((size_t)(b * HKV_ + (h - HQ_)) * S_ + s) * D_ + 2 * lane) = pack;
        }
    }
    {
        int h = wave;
        u32 xw = *(const u32*)(base + (HQ_ + HKV_) * 128 + h * 128 + 2 * lane);
        *(u32*)(vb + ((size_t)(b * HKV_ + h) * S_ + s) * D_ + 2 * lane) = xw;
    }
}

// ---------------------------------------------------------------- V transpose: (B,HKV,S,D) -> (B,HKV,D,S)
__global__ __launch_bounds__(256) void transpose_v(const u16* __restrict__ vb,
                                                   u16* __restrict__ vtb) {
    __shared__ u16 t[64][72];
    const int s0 = blockIdx.x * 64, d0 = blockIdx.y * 64, bh = blockIdx.z;
    const u16* src = vb  + (size_t)bh * S_ * D_;
    u16*       dst = vtb + (size_t)bh * D_ * S_;
    const int tid = threadIdx.x;

    {
        int r = tid >> 3, c8 = (tid & 7) * 8;
        #pragma unroll
        for (int p = 0; p < 2; p++) {
            int rr = r + p * 32;
            *(uint4*)&t[rr][c8] = *(const uint4*)(src + (size_t)(s0 + rr) * D_ + d0 + c8);
        }
    }
    __syncthreads();
    {
        int dd = tid & 63;
        int sb = (tid >> 6) * 8;
        #pragma unroll
        for (int p = 0; p < 2; p++) {
            int ss8 = sb + p * 32;
            union { u16 u[8]; uint4 v; } pk;
            #pragma unroll
            for (int j = 0; j < 8; j++) pk.u[j] = t[ss8 + j][dd];
            *(uint4*)(dst + (size_t)(d0 + dd) * S_ + s0 + ss8) = pk.v;
        }
    }
}

// ---------------------------------------------------------------- causal GQA flash attention v8 (R13/R16-proven best: 76.3us)
// K: rows 256B, 4-bit swizzle (row&15)<<4 -> 2-way (free).
// V: paired-row layout [64 rows x 256B] (raw=(d&1)*128+kv*2), ^(row&15)<<4
// -> 2-way (free). Stage source carries the inverse permutation (rule #21).
// NOTE: the sc = partial+partial adds MUST stay before the V-fragment reads
// (R17 lesson: reordering extends partial live ranges across vf -> spill,
// WRITE_SIZE 16->27MB, 76->114us). This schedule is the live-range boundary.
__global__ __launch_bounds__(256, 2) void attn_fwd3(const u16* __restrict__ qb,
                                                    const u16* __restrict__ kb,
                                                    const u16* __restrict__ vtb,
                                                    u16* __restrict__ attn) {
    __shared__ __align__(16) u16 Ks[2][64 * 128];   // 32KB (reused as O bounce)
    __shared__ __align__(16) u16 Vs[2][64 * 128];   // 32KB, [64 rows][256B]

    const int bh  = blockIdx.y;
    const int qt  = (bh < 16) ? (15 - (int)blockIdx.x) : (int)blockIdx.x;
    const int b   = bh >> 4, hq = bh & 15, hkv = hq >> 2;
    const int tid = threadIdx.x;
    const int wave = tid >> 6, lane = tid & 63;
    const int l31 = lane & 31, hi = lane >> 5;
    const int swzK = (l31 & 15) << 4;               // 4-bit K swizzle
    const int swzO = (l31 & 7) << 4;                // epilogue bounce

    const u16* Q  = qb  + (size_t)(b * HQ_  + hq ) * S_ * D_;
    const u16* Kp = kb  + (size_t)(b * HKV_ + hkv) * S_ * D_;
    const u16* Vt = vtb + (size_t)(b * HKV_ + hkv) * D_ * S_;
    const int q0w = qt * 128 + wave * 32;
    const int qg  = q0w + l31;            // this lane's q row

    int kSrc[4], vSrc[4], cLds[4];
    #pragma unroll
    for (int p = 0; p < 4; p++) {
        int c = tid + p * 256;
        int kr = c >> 4;                                   // K row 0..63
        int kc = ((c & 15) * 16) ^ ((kr & 15) << 4);       // bytes in row
        kSrc[p] = kr * D_ + (kc >> 1);
        int vr = c >> 4;                                   // V LDS row 0..63
        int raw = (c & 15) ^ (vr & 15);                    // 16B slot pre-swizzle
        int vd = 2 * vr + (raw >> 3);                      // d index
        vSrc[p] = vd * S_ + (raw & 7) * 8;                 // elem offset (kv chunk)
        cLds[p] = c * 16;
    }

    auto STAGE = [&](int buf, int kv0s) {
        const u16* kbase = Kp + (size_t)kv0s * D_;
        const u16* vbase = Vt + kv0s;
        #pragma unroll
        for (int p = 0; p < 4; p++)
            __builtin_amdgcn_global_load_lds(
                (const __attribute__((address_space(1))) void*)(kbase + kSrc[p]),
                (__attribute__((address_space(3))) void*)((char*)Ks[buf] + cLds[p]), 16, 0, 0);
        #pragma unroll
        for (int p = 0; p < 4; p++)
            __builtin_amdgcn_global_load_lds(
                (const __attribute__((address_space(1))) void*)(vbase + vSrc[p]),
                (__attribute__((address_space(3))) void*)((char*)Vs[buf] + cLds[p]), 16, 0, 0);
    };

    bf16x8 qf[8];
    #pragma unroll
    for (int ds = 0; ds < 8; ds++)
        qf[ds] = *(const bf16x8*)(Q + (size_t)qg * D_ + ds * 16 + hi * 8);

    float m_run = -1e30f, l_run = 0.f;
    f32x16 oacc[4] = {};

    const int nkt = 2 * qt + 2;
    STAGE(0, 0);

    for (int kt = 0; kt < nkt; kt++) {
        const int cur = kt & 1;
        const int kv0 = kt * 64;
        if (kt + 1 < nkt) {
            STAGE(cur ^ 1, kv0 + 64);
            asm volatile("s_waitcnt vmcnt(8)" ::: "memory");
        } else {
            asm volatile("s_waitcnt vmcnt(0)" ::: "memory");
        }
        __builtin_amdgcn_s_barrier();

        // ---- batch K-fragment reads (2-way banked -> conflict-free)
        const char* ksb = (const char*)Ks[cur];
        const char* vsb = (const char*)Vs[cur];
        const char* rb0 = ksb + l31 * 256;
        const char* rb1 = rb0 + 32 * 256;
        bf16x8 kA[8], kB[8];
        #pragma unroll
        for (int ds = 0; ds < 8; ds++) kA[ds] = *(const bf16x8*)(rb0 + ((ds * 32 + hi * 16) ^ swzK));
        #pragma unroll
        for (int ds = 0; ds < 8; ds++) kB[ds] = *(const bf16x8*)(rb1 + ((ds * 32 + hi * 16) ^ swzK));

        f32x16 s0a = {}, s0b = {}, s1a = {}, s1b = {};
        __builtin_amdgcn_s_setprio(1);
        #pragma unroll
        for (int ds = 0; ds < 4; ds++) {
            s0a = __builtin_amdgcn_mfma_f32_32x32x16_bf16(kA[ds],     qf[ds],     s0a, 0, 0, 0);
            s0b = __builtin_amdgcn_mfma_f32_32x32x16_bf16(kA[ds + 4], qf[ds + 4], s0b, 0, 0, 0);
            s1a = __builtin_amdgcn_mfma_f32_32x32x16_bf16(kB[ds],     qf[ds],     s1a, 0, 0, 0);
            s1b = __builtin_amdgcn_mfma_f32_32x32x16_bf16(kB[ds + 4], qf[ds + 4], s1b, 0, 0, 0);
        }
        __builtin_amdgcn_s_setprio(0);
        f32x16 sc[2];
        sc[0] = s0a + s0b;
        sc[1] = s1a + s1b;

        // ---- V fragments from paired-row layout (2-way banked -> free)
        bf16x8 vf[4][4];
        {
            const int vrow = (l31 >> 1);
            const int vswz = vrow << 4;
            const int dlo  = (l31 & 1) << 7;
            #pragma unroll
            for (int ks = 0; ks < 4; ks++)
                #pragma unroll
                for (int d4 = 0; d4 < 4; d4++)
                    vf[ks][d4] = *(const bf16x8*)(vsb + (d4 * 16 + vrow) * 256
                                                      + ((dlo | (ks * 32 + hi * 16)) ^ vswz));
        }
        __builtin_amdgcn_s_barrier();

        if (kv0 + 63 > q0w) {
            #pragma unroll
            for (int blk = 0; blk < 2; blk++)
                #pragma unroll
                for (int r = 0; r < 16; r++) {
                    int kvg = kv0 + blk * 32 + (r & 3) + 8 * (r >> 2) + 4 * hi;
                    if (kvg > qg) sc[blk][r] = -1e30f;
                }
        }

        float t16[16];
        #pragma unroll
        for (int r = 0; r < 16; r++) t16[r] = fmaxf(sc[0][r], sc[1][r]);
        #pragma unroll
        for (int r = 0; r < 8; r++) t16[r] = fmaxf(t16[r], t16[r + 8]);
        #pragma unroll
        for (int r = 0; r < 4; r++) t16[r] = fmaxf(t16[r], t16[r + 4]);
        float mt = fmaxf(fmaxf(t16[0], t16[1]), fmaxf(t16[2], t16[3]));
        mt = fmaxf(mt, __shfl_xor(mt, 32));

        bool noDefer = !__all(mt <= m_run + 8.0f);
        float mnew = m_run;
        if (noDefer) {
            mnew = fmaxf(m_run, mt);
            float alpha = __builtin_amdgcn_exp2f(m_run - mnew);
            l_run *= alpha;
            #pragma unroll
            for (int d4 = 0; d4 < 4; d4++)
                #pragma unroll
                for (int r = 0; r < 16; r++) oacc[d4][r] *= alpha;
            m_run = mnew;
        }

        float la = 0.f;
        u32 pk0[8], pk1[8];
        #pragma unroll
        for (int g = 0; g < 4; g++)
            #pragma unroll
            for (int e = 0; e < 2; e++) {
                float a0 = __builtin_amdgcn_exp2f(sc[0][g * 4 + 2 * e]     - mnew);
                float b0 = __builtin_amdgcn_exp2f(sc[0][g * 4 + 2 * e + 1] - mnew);
                float a1 = __builtin_amdgcn_exp2f(sc[1][g * 4 + 2 * e]     - mnew);
                float b1 = __builtin_amdgcn_exp2f(sc[1][g * 4 + 2 * e + 1] - mnew);
                la += (a0 + b0) + (a1 + b1);
                pk0[g * 2 + e] = (u32)f2b(a0) | ((u32)f2b(b0) << 16);
                pk1[g * 2 + e] = (u32)f2b(a1) | ((u32)f2b(b1) << 16);
            }
        la += __shfl_xor(la, 32);
        l_run += la;

        u32 qk0[8], qk1[8];
        #pragma unroll
        for (int i = 0; i < 8; i++) {
            qk0[i] = __shfl_xor(pk0[i], 32);
            qk1[i] = __shfl_xor(pk1[i], 32);
        }

        #pragma unroll
        for (int ks = 0; ks < 4; ks++) {
            const int i0 = (ks & 1) * 4;
            union { u32 w[4]; bf16x8 v; } pfv;
            if (ks & 2) {
                pfv.w[0] = hi ? qk1[i0 + 2] : pk1[i0 + 0];
                pfv.w[1] = hi ? qk1[i0 + 3] : pk1[i0 + 1];
                pfv.w[2] = hi ? pk1[i0 + 2] : qk1[i0 + 0];
                pfv.w[3] = hi ? pk1[i0 + 3] : qk1[i0 + 1];
            } else {
                pfv.w[0] = hi ? qk0[i0 + 2] : pk0[i0 + 0];
                pfv.w[1] = hi ? qk0[i0 + 3] : pk0[i0 + 1];
                pfv.w[2] = hi ? pk0[i0 + 2] : qk0[i0 + 0];
                pfv.w[3] = hi ? pk0[i0 + 3] : qk0[i0 + 1];
            }
            __builtin_amdgcn_s_setprio(1);
            #pragma unroll
            for (int d4 = 0; d4 < 4; d4++)
                oacc[d4] = __builtin_amdgcn_mfma_f32_32x32x16_bf16(vf[ks][d4], pfv.v, oacc[d4], 0, 0, 0);
            __builtin_amdgcn_s_setprio(0);
        }
    }

    const float inv = 1.0f / l_run;
    u16* sl = (u16*)Ks + wave * (32 * 128);
    #pragma unroll
    for (int d4 = 0; d4 < 4; d4++)
        #pragma unroll
        for (int rp = 0; rp < 8; rp++) {
            int dbyte = d4 * 64 + 16 * (rp >> 1) + 8 * hi + 4 * (rp & 1);
            u32 w = (u32)f2b(oacc[d4][rp * 2] * inv)
                  | ((u32)f2b(oacc[d4][rp * 2 + 1] * inv) << 16);
            *(u32*)((char*)sl + l31 * 256 + (dbyte ^ swzO)) = w;
        }
    #pragma unroll
    for (int j = 0; j < 8; j++) {
        int c = lane + j * 64;
        int qL = c >> 4, dc = c & 15;
        uint4 v = *(uint4*)((char*)sl + qL * 256 + ((dc * 16) ^ ((qL & 7) << 4)));
        int qrow = qt * 128 + wave * 32 + qL;
        *(uint4*)(attn + (size_t)(b * S_ + qrow) * (HQ_ * D_) + hq * D_ + dc * 8) = v;
    }
}

// ---------------------------------------------------------------- launcher
extern "C" void kernel_launch(void* const* d_in, const int* in_sizes, int n_in,
                              void* d_out, int out_size, void* d_ws, size_t ws_size,
                              hipStream_t stream) {
    const float* hidden = (const float*)d_in[0];
    const float* cosb   = (const float*)d_in[1];
    const float* sinb   = (const float*)d_in[2];
    const float* qkvw   = (const float*)d_in[3];
    const float* nw     = (const float*)d_in[4];
    const float* ow     = (const float*)d_in[5];
    float* out = (float*)d_out;

    const size_t M  = (size_t)B_ * S_;             // 4096
    char* ws = (char*)d_ws;
    size_t off = 0;
    u16*   hb    = (u16*)(ws + off); off += M * HID * 2;                     // 16 MB (reused as attn)
    u16*   wqkvb = (u16*)(ws + off); off += (size_t)NQKV * HID * 2;          // 12 MB
    u16*   wob   = (u16*)(ws + off); off += (size_t)HID * (HQ_ * D_) * 2;    // 8 MB
    u16*   qkvb  = (u16*)(ws + off); off += M * NQKV * 2;                    // 24 MB (bf16)
    u16*   qb2   = (u16*)(ws + off); off += (size_t)B_ * HQ_  * S_ * D_ * 2; // 16 MB
    u16*   kb2   = (u16*)(ws + off); off += (size_t)B_ * HKV_ * S_ * D_ * 2; // 4 MB
    u16*   vb2   = (u16*)(ws + off); off += (size_t)B_ * HKV_ * S_ * D_ * 2; // 4 MB
    u16*   vtb   = (u16*)(ws + off); off += (size_t)B_ * HKV_ * S_ * D_ * 2; // 4 MB
    u16*   attn  = hb;

    // fused conversions (1 launch)
    {
        int n0 = (int)(M * HID / 4);
        int n1 = NQKV * HID / 4;
        int n2 = HID * (HQ_ * D_) / 4;
        int nt = n0 + n1 + n2;
        cvt3_f32_bf16<<<(nt + 255) / 256, 256, 0, stream>>>(hidden, hb, n0,
                                                            qkvw, wqkvb, n1,
                                                            ow, wob, n2);
    }

    // QKV projection -> bf16 qkv (grid 32x24 = 768 blocks)
    gemm128sq<true><<<dim3(M / 128, NQKV / 128), 256, 0, stream>>>(
        hb, wqkvb, qkvb, (int)M, NQKV, HID);

    rope_norm_split<<<(int)M, 256, 0, stream>>>(qkvb, cosb, sinb, nw, qb2, kb2, vb2);

    transpose_v<<<dim3(S_ / 64, D_ / 64, B_ * HKV_), 256, 0, stream>>>(vb2, vtb);

    attn_fwd3<<<dim3(16, B_ * HQ_), 256, 0, stream>>>(qb2, kb2, vtb, attn);

    // output projection -> f32 d_out (grid 32x16 = 512 blocks)
    gemm128sq<false><<<dim3(M / 128, HID / 128), 256, 0, stream>>>(
        attn, wob, out, (int)M, HID, HQ_ * D_);
}